// Round 4
// baseline (361.245 us; speedup 1.0000x reference)
//
#include <hip/hip_runtime.h>
#include <cstdint>
#include <cstddef>

#define DECAYF 0.99f
#define OMDF   0.01f
#define EPSF   1e-5f
#define MARGIN 0.075f  // fp16 score-error bound

constexpr int N_ROWS = 64 * 2048;   // 131072
constexpr int D      = 128;
constexpr int K      = 1024;
constexpr int RSLICE = 8;           // code slices in rescore (128 codes each)
constexpr int CHUNK  = 64;          // rowlist rows per segsum block
constexpr int MROWS  = 128;         // rows per mfma_dist block (4 blocks/CU)

typedef _Float16 f16x8 __attribute__((ext_vector_type(8)));  // 8 f16 = 4 VGPRs
typedef __attribute__((ext_vector_type(4))) float f32x4;

union U8 { f16x8 v; uint4 u; };

__device__ __forceinline__ unsigned short f2h(float f) {
    union { _Float16 h; unsigned short u; } cv;
    cv.h = (_Float16)f;   // RNE
    return cv.u;
}

// ---------------------------------------------------------------------------
// Convert embed fp32 -> fp16 with 2x baked in (exact scale): eh = f16(2*e)
// ---------------------------------------------------------------------------
__global__ __launch_bounds__(256) void convert_e(const float* __restrict__ e,
                                                 unsigned short* __restrict__ eh) {
    int i = blockIdx.x * 256 + threadIdx.x;          // K*D/8 threads
    const float4* e4 = (const float4*)e;
    float4 a = e4[2 * i], b = e4[2 * i + 1];
    uint4 o;
    o.x = (unsigned)f2h(2.f * a.x) | ((unsigned)f2h(2.f * a.y) << 16);
    o.y = (unsigned)f2h(2.f * a.z) | ((unsigned)f2h(2.f * a.w) << 16);
    o.z = (unsigned)f2h(2.f * b.x) | ((unsigned)f2h(2.f * b.y) << 16);
    o.w = (unsigned)f2h(2.f * b.z) | ((unsigned)f2h(2.f * b.w) << 16);
    ((uint4*)eh)[i] = o;
}

// ---------------------------------------------------------------------------
// cnorm[k] = ||embed[k]||^2 (fp32), plus packed f16 hi/lo split of -cnorm
// for MFMA-folded bias: cnp[k] = lo16(-cn_hi) | (lo16(-cn_lo) << 16)
// ---------------------------------------------------------------------------
__global__ __launch_bounds__(256) void cnorm_kernel(const float* __restrict__ embed,
                                                    float* __restrict__ cnorm,
                                                    unsigned* __restrict__ cnp) {
    int k = blockIdx.x * 256 + threadIdx.x;
    if (k >= K) return;
    const float4* e4 = (const float4*)(embed + (size_t)k * D);
    float a0 = 0.f, a1 = 0.f, a2 = 0.f, a3 = 0.f;
#pragma unroll
    for (int i = 0; i < D / 4; ++i) {
        float4 v = e4[i];
        a0 += v.x * v.x; a1 += v.y * v.y; a2 += v.z * v.z; a3 += v.w * v.w;
    }
    float cn = (a0 + a1) + (a2 + a3);
    cnorm[k] = cn;
    unsigned short h = f2h(-cn);
    union { unsigned short u; _Float16 hf; } cvh; cvh.u = h;
    float hr = (float)cvh.hf;
    unsigned short l = f2h(-cn - hr);
    cnp[k] = (unsigned)h | ((unsigned)l << 16);
}

// ---------------------------------------------------------------------------
// MFMA distance (fp16) + approx argmax with best/best2 margin flagging.
//  - 128 rows/block -> 1024 blocks = 4 blocks/CU = 4 waves/SIMD (2x occupancy)
//  - -||e||^2 folded into MFMA via hi/lo f16 bias row
//  - ping-pong double-buffered B prefetch, strength-reduced pointers
// ---------------------------------------------------------------------------
__global__ __launch_bounds__(256, 4) void mfma_dist(const float* __restrict__ x,
                                                    const unsigned short* __restrict__ eh,
                                                    const unsigned* __restrict__ cnp,
                                                    float* __restrict__ out_idx,
                                                    int* __restrict__ idx_i32,
                                                    int* __restrict__ flag_cnt,
                                                    int* __restrict__ flag_list) {
    __shared__ float sb1[MROWS * 17];
    __shared__ float sb2[MROWS * 17];
    __shared__ float sid[MROWS * 17];

    const int tid = threadIdx.x;
    const int wave = tid >> 6;
    const int lane = tid & 63;
    const int l15 = lane & 15;
    const int quad = lane >> 4;
    const int rowbase = blockIdx.x * MROWS + wave * 32;

    // preload A-frags: 2 sets x 4 d-chunks, convert fp32->fp16 inline
    f16x8 a[2][4];
    {
        const float4* x4 = (const float4*)x;
#pragma unroll
        for (int s = 0; s < 2; ++s) {
            int row = rowbase + s * 16 + l15;
#pragma unroll
            for (int c = 0; c < 4; ++c) {
                size_t b4 = ((size_t)row * D + c * 32 + quad * 8) >> 2;
                float4 p = x4[b4], q = x4[b4 + 1];
                f16x8 f;
                f[0] = (_Float16)p.x; f[1] = (_Float16)p.y;
                f[2] = (_Float16)p.z; f[3] = (_Float16)p.w;
                f[4] = (_Float16)q.x; f[5] = (_Float16)q.y;
                f[6] = (_Float16)q.z; f[7] = (_Float16)q.w;
                a[s][c] = f;
            }
        }
    }

    // constant A-frag for the bias row: k-slots 0,1 = 1.0 (quad 0 lanes only)
    U8 acn;
    acn.u.x = (quad == 0) ? 0x3C003C00u : 0u;
    acn.u.y = 0u; acn.u.z = 0u; acn.u.w = 0u;

    float b1[2][4], b2[2][4], idf[2][4];
#pragma unroll
    for (int s = 0; s < 2; ++s)
#pragma unroll
        for (int r = 0; r < 4; ++r) { b1[s][r] = -3.4e38f; b2[s][r] = -3.4e38f; idf[s][r] = 0.f; }

    // strength-reduced B walk: per-lane base, +16*D per chunk
    const unsigned short* pb = eh + l15 * D + quad * 8;
    const unsigned* pc = cnp + l15;

    auto load_b = [&](f16x8* dst, unsigned& cnw) {
#pragma unroll
        for (int c = 0; c < 4; ++c)
            dst[c] = *(const f16x8*)(pb + c * 32);
        cnw = *pc;
        pb += 16 * D;
        pc += 16;
    };

    auto compute = [&](const f16x8* bfr, unsigned cnw, float colf) {
        U8 bcn;
        bcn.u.x = (quad == 0) ? cnw : 0u;
        bcn.u.y = 0u; bcn.u.z = 0u; bcn.u.w = 0u;
        f32x4 zero = {0.f, 0.f, 0.f, 0.f};
        f32x4 cnacc = __builtin_amdgcn_mfma_f32_16x16x32_f16(acn.v, bcn.v, zero, 0, 0, 0);
#pragma unroll
        for (int s = 0; s < 2; ++s) {
            f32x4 acc = cnacc;
#pragma unroll
            for (int c = 0; c < 4; ++c)
                acc = __builtin_amdgcn_mfma_f32_16x16x32_f16(a[s][c], bfr[c], acc, 0, 0, 0);
#pragma unroll
            for (int r = 0; r < 4; ++r) {
                float sc = acc[r];               // = 2*x.e - ||e||^2 directly
                float old = b1[s][r];
                b1[s][r] = fmaxf(old, sc);
                b2[s][r] = fmaxf(fminf(sc, old), b2[s][r]);
                idf[s][r] = (sc > old) ? colf : idf[s][r];
            }
        }
    };

    f16x8 bA[4], bB[4];
    unsigned cnA, cnB;
    load_b(bA, cnA);                              // chunk 0
    float colA = (float)l15;
    float colB = (float)(l15 + 16);

    for (int it = 0; it < K / 32 - 1; ++it) {     // 31 iterations = chunks 0..61
        load_b(bB, cnB);                          // prefetch odd chunk
        compute(bA, cnA, colA);
        colA += 32.f;
        load_b(bA, cnA);                          // prefetch next even chunk
        compute(bB, cnB, colB);
        colB += 32.f;
    }
    load_b(bB, cnB);                              // chunk 63
    compute(bA, cnA, colA);                       // chunk 62
    compute(bB, cnB, colB);                       // chunk 63

    // dump per-lane candidates: row lr has 16 candidates (one per l15)
#pragma unroll
    for (int s = 0; s < 2; ++s)
#pragma unroll
        for (int r = 0; r < 4; ++r) {
            int lr = wave * 32 + s * 16 + quad * 4 + r;
            sb1[lr * 17 + l15] = b1[s][r];
            sb2[lr * 17 + l15] = b2[s][r];
            sid[lr * 17 + l15] = idf[s][r];
        }
    __syncthreads();

    // one thread per row: merge 16 (b1,b2,idx) candidates
    if (tid < MROWS) {
        float bs = sb1[tid * 17], ss = sb2[tid * 17], bi = sid[tid * 17];
#pragma unroll
        for (int j = 1; j < 16; ++j) {
            float v = sb1[tid * 17 + j];
            float w = sb2[tid * 17 + j];
            float id = sid[tid * 17 + j];
            if (v > bs) { ss = fmaxf(bs, w); bi = id; bs = v; }
            else {
                ss = fmaxf(ss, v);
                if (v == bs && id < bi) bi = id;
            }
        }
        int grow = blockIdx.x * MROWS + tid;
        out_idx[grow] = bi;
        idx_i32[grow] = (int)bi;
        if (bs - ss < MARGIN) {
            int p = atomicAdd(flag_cnt, 1);
            flag_list[p] = grow;
        }
    }
}

// ---------------------------------------------------------------------------
// Exact fp32 rescore of flagged rows, CODE-SLICED across blocks.
// grid = (chunks grid-stride, RSLICE). Each block: 128 rows x 128 codes.
// Partial per-row argmax merged via packed u64 atomicMax:
//   key = orderable(score) << 32 | (0xFFFF - idx)   (max score, min idx on tie)
// ---------------------------------------------------------------------------
__global__ __launch_bounds__(256, 1) void rescore_part(const float* __restrict__ x,
                                                       const float* __restrict__ embed,
                                                       const float* __restrict__ cnorm,
                                                       const int* __restrict__ flag_cnt,
                                                       const int* __restrict__ flag_list,
                                                       unsigned long long* __restrict__ rkey) {
    __shared__ float xs[128][132];
    __shared__ float es[128][132];

    const int tid = threadIdx.x;
    const int tx = tid & 15;
    const int ty = tid >> 4;
    const int sl = blockIdx.y;                 // code slice: [sl*128, sl*128+128)
    const int cnt = *flag_cnt;
    const int nch = (cnt + 127) >> 7;

    for (int ch = blockIdx.x; ch < nch; ch += gridDim.x) {
        __syncthreads();
        // stage 128 flagged x rows
        {
            const float4* x4 = (const float4*)x;
#pragma unroll
            for (int it = 0; it < 16; ++it) {
                int idx = it * 256 + tid;
                int slot = idx >> 5, c4 = idx & 31;
                int fi = ch * 128 + slot;
                int grow = flag_list[fi < cnt ? fi : cnt - 1];
                float4 v = x4[(size_t)grow * 32 + c4];
                *(float4*)&xs[slot][c4 * 4] = v;
            }
        }
        // stage this slice's 128 embed rows
        {
            const float4* e4 = (const float4*)embed;
            const size_t base4 = (size_t)sl * 128 * 32;
#pragma unroll
            for (int it = 0; it < 16; ++it) {
                int idx = it * 256 + tid;
                int row = idx >> 5, c4 = idx & 31;
                float4 v = e4[base4 + idx];
                *(float4*)&es[row][c4 * 4] = v;
            }
        }
        float cn[8];
#pragma unroll
        for (int c = 0; c < 8; ++c) cn[c] = cnorm[sl * 128 + tx + 16 * c];
        __syncthreads();

        float acc[8][8];
#pragma unroll
        for (int r = 0; r < 8; ++r)
#pragma unroll
            for (int c = 0; c < 8; ++c) acc[r][c] = 0.f;

#pragma unroll 2
        for (int d4 = 0; d4 < 32; ++d4) {
            float4 av[8], bv[8];
#pragma unroll
            for (int r = 0; r < 8; ++r) av[r] = *(const float4*)&xs[ty + 16 * r][4 * d4];
#pragma unroll
            for (int c = 0; c < 8; ++c) bv[c] = *(const float4*)&es[tx + 16 * c][4 * d4];
#pragma unroll
            for (int r = 0; r < 8; ++r)
#pragma unroll
                for (int c = 0; c < 8; ++c) {
                    acc[r][c] = fmaf(av[r].x, bv[c].x, acc[r][c]);
                    acc[r][c] = fmaf(av[r].y, bv[c].y, acc[r][c]);
                    acc[r][c] = fmaf(av[r].z, bv[c].z, acc[r][c]);
                    acc[r][c] = fmaf(av[r].w, bv[c].w, acc[r][c]);
                }
        }

        float best[8];
        int bidx[8];
#pragma unroll
        for (int r = 0; r < 8; ++r) { best[r] = -3.4e38f; bidx[r] = 0; }
#pragma unroll
        for (int r = 0; r < 8; ++r)
#pragma unroll
            for (int c = 0; c < 8; ++c) {
                float s = 2.0f * acc[r][c] - cn[c];
                // codes ascend with c, so strict > keeps the lowest tied index
                if (s > best[r]) { best[r] = s; bidx[r] = sl * 128 + tx + 16 * c; }
            }

        __syncthreads();
        float* sbest = &es[0][0];
        int*   sidx  = (int*)&xs[0][0];
#pragma unroll
        for (int r = 0; r < 8; ++r) {
            int row = ty + 16 * r;
            sbest[row * 16 + tx] = best[r];
            sidx[row * 16 + tx] = bidx[r];
        }
        __syncthreads();
        if (tid < 128) {
            float bs = sbest[tid * 16];
            int bi = sidx[tid * 16];
#pragma unroll
            for (int j = 1; j < 16; ++j) {
                float s = sbest[tid * 16 + j];
                int id = sidx[tid * 16 + j];
                if (s > bs || (s == bs && id < bi)) { bs = s; bi = id; }
            }
            int fi = ch * 128 + tid;
            if (fi < cnt) {
                unsigned ub = __float_as_uint(bs);
                ub = (ub & 0x80000000u) ? ~ub : (ub | 0x80000000u);
                unsigned long long key =
                    ((unsigned long long)ub << 32) | (unsigned)(0xFFFFu - bi);
                atomicMax(&rkey[fi], key);
            }
        }
    }
}

__global__ __launch_bounds__(256) void rescore_final(const int* __restrict__ flag_cnt,
                                                     const int* __restrict__ flag_list,
                                                     const unsigned long long* __restrict__ rkey,
                                                     float* __restrict__ out_idx,
                                                     int* __restrict__ idx_i32) {
    const int cnt = *flag_cnt;
    for (int i = blockIdx.x * 256 + threadIdx.x; i < cnt; i += gridDim.x * 256) {
        unsigned long long key = rkey[i];
        int bi = 0xFFFF - (int)(key & 0xFFFFFFFFull);
        int grow = flag_list[i];
        out_idx[grow] = (float)bi;
        idx_i32[grow] = bi;
    }
}

// ---------------------------------------------------------------------------
// Histogram of final indices (LDS-privatized)
// ---------------------------------------------------------------------------
__global__ __launch_bounds__(256) void hist_kernel(const int* __restrict__ idx_i32,
                                                   int* __restrict__ counts_i) {
    __shared__ int h[K];
    for (int i = threadIdx.x; i < K; i += 256) h[i] = 0;
    __syncthreads();
    for (int row = blockIdx.x * 256 + threadIdx.x; row < N_ROWS; row += gridDim.x * 256)
        atomicAdd(&h[idx_i32[row]], 1);
    __syncthreads();
    for (int i = threadIdx.x; i < K; i += 256)
        if (h[i]) atomicAdd(&counts_i[i], h[i]);
}

// ---------------------------------------------------------------------------
// scan counts -> offsets/cursor; ncs, total, smoothed (1 block, 1024 thr)
// ---------------------------------------------------------------------------
__global__ __launch_bounds__(1024) void scan_cluster_kernel(const int* __restrict__ counts_i,
                                                            const float* __restrict__ cluster_size,
                                                            int* __restrict__ offsets,
                                                            int* __restrict__ cursor,
                                                            float* __restrict__ out_ncs,
                                                            float* __restrict__ smoothed) {
    __shared__ int s[1024];
    __shared__ float red[16];
    __shared__ float total_s;
    int k = threadIdx.x;
    int c = counts_i[k];
    s[k] = c;
    __syncthreads();
    for (int off = 1; off < 1024; off <<= 1) {
        int v = (k >= off) ? s[k - off] : 0;
        __syncthreads();
        s[k] += v;
        __syncthreads();
    }
    int offx = s[k] - c;   // exclusive
    offsets[k] = offx;
    cursor[k] = offx;

    float ncs = cluster_size[k] * DECAYF + OMDF * (float)c;
    out_ncs[k] = ncs;

    float v = ncs;
#pragma unroll
    for (int off = 32; off >= 1; off >>= 1) v += __shfl_down(v, off, 64);
    if ((k & 63) == 0) red[k >> 6] = v;
    __syncthreads();
    if (k < 16) {
        float t = red[k];
#pragma unroll
        for (int off = 8; off >= 1; off >>= 1) t += __shfl_down(t, off, 16);
        if (k == 0) total_s = t;
    }
    __syncthreads();
    float total = total_s;
    smoothed[k] = (ncs + EPSF) / (total + (float)K * EPSF) * total;
}

// ---------------------------------------------------------------------------
// scatter row ids (and their code) into per-code segments
// ---------------------------------------------------------------------------
__global__ __launch_bounds__(256) void scatter_kernel(const int* __restrict__ idx_i32,
                                                      int* __restrict__ cursor,
                                                      int* __restrict__ rowlist,
                                                      int* __restrict__ codelist) {
    int row = blockIdx.x * 256 + threadIdx.x;
    int code = idx_i32[row];
    int pos = atomicAdd(&cursor[code], 1);
    rowlist[pos] = row;
    codelist[pos] = code;
}

// ---------------------------------------------------------------------------
// Flat segmented gather-sum: each block owns exactly CHUNK consecutive
// rowlist entries (perfect balance). Register run-accumulation; atomic
// flush only at run boundaries.
// ---------------------------------------------------------------------------
__global__ __launch_bounds__(128) void segsum_flat(const float* __restrict__ x,
                                                   const int* __restrict__ rowlist,
                                                   const int* __restrict__ codelist,
                                                   float* __restrict__ embed_sum) {
    const int d = threadIdx.x;
    const int lo = blockIdx.x * CHUNK;

    float acc = 0.f;
    int cur = codelist[lo];
    for (int i = lo; i < lo + CHUNK; i += 8) {
        int r[8], c[8];
        float v[8];
#pragma unroll
        for (int j = 0; j < 8; ++j) {
            r[j] = rowlist[i + j];
            c[j] = codelist[i + j];
        }
#pragma unroll
        for (int j = 0; j < 8; ++j) v[j] = x[(size_t)r[j] * D + d];
#pragma unroll
        for (int j = 0; j < 8; ++j) {
            if (c[j] != cur) {
                atomicAdd(&embed_sum[(size_t)cur * D + d], acc);
                acc = 0.f;
                cur = c[j];
            }
            acc += v[j];
        }
    }
    atomicAdd(&embed_sum[(size_t)cur * D + d], acc);
}

// ---------------------------------------------------------------------------
// new_embed_avg / new_embed
// ---------------------------------------------------------------------------
__global__ __launch_bounds__(256) void embed_update_kernel(const float* __restrict__ embed_avg,
                                                           const float* __restrict__ embed_sum,
                                                           const float* __restrict__ smoothed,
                                                           float* __restrict__ out_nea,
                                                           float* __restrict__ out_ne) {
    int t = blockIdx.x * 256 + threadIdx.x;
    float4 ea = ((const float4*)embed_avg)[t];
    float4 es = ((const float4*)embed_sum)[t];
    float sm = smoothed[t >> 5];
    float4 nea;
    nea.x = ea.x * DECAYF + OMDF * es.x;
    nea.y = ea.y * DECAYF + OMDF * es.y;
    nea.z = ea.z * DECAYF + OMDF * es.z;
    nea.w = ea.w * DECAYF + OMDF * es.w;
    ((float4*)out_nea)[t] = nea;
    float4 ne;
    ne.x = nea.x / sm; ne.y = nea.y / sm; ne.z = nea.z / sm; ne.w = nea.w / sm;
    ((float4*)out_ne)[t] = ne;
}

// ---------------------------------------------------------------------------
// quantized[row] = embed[idx[row]]  (runs last: overwrites rkey/codelist scratch)
// ---------------------------------------------------------------------------
__global__ __launch_bounds__(256) void gather_kernel(const float* __restrict__ embed,
                                                     const int* __restrict__ idx_i32,
                                                     float* __restrict__ quant) {
    int t = blockIdx.x * 256 + threadIdx.x;
    int row = t >> 5;
    int j = t & 31;
    int k = idx_i32[row];
    ((float4*)quant)[(size_t)row * 32 + j] = ((const float4*)embed)[(size_t)k * 32 + j];
}

// ---------------------------------------------------------------------------
extern "C" void kernel_launch(void* const* d_in, const int* in_sizes, int n_in,
                              void* d_out, int out_size, void* d_ws, size_t ws_size,
                              hipStream_t stream) {
    const float* x            = (const float*)d_in[0];
    const float* embed        = (const float*)d_in[1];
    const float* embed_avg    = (const float*)d_in[2];
    const float* cluster_size = (const float*)d_in[3];

    float* out       = (float*)d_out;
    float* out_quant = out;
    float* out_idx   = out_quant + (size_t)N_ROWS * D;
    float* out_ne    = out_idx + N_ROWS;
    float* out_ncs   = out_ne + (size_t)K * D;
    float* out_nea   = out_ncs + K;

    // scratch in the quantized output region (overwritten by gather_kernel last):
    //   rkey: u64 argmax keys for flagged rows (1 MB)
    //   codelist: per-rowlist-slot code ids (0.5 MB)
    unsigned long long* rkey = (unsigned long long*)out_quant;
    int* codelist = (int*)(rkey + N_ROWS);

    // workspace (~2.4 MB)
    int*   counts_i  = (int*)d_ws;                        // K
    int*   flag_cnt  = counts_i + K;                      // 1 (+3 pad)
    int*   idx_i32   = counts_i + K + 4;                  // N
    int*   flag_list = idx_i32 + N_ROWS;                  // N
    int*   offsets   = flag_list + N_ROWS;                // K
    int*   cursor    = offsets + K;                       // K
    int*   rowlist   = cursor + K;                        // N
    float* cnorm     = (float*)(rowlist + N_ROWS);        // K
    float* smoothed  = cnorm + K;                         // K
    unsigned* cnp    = (unsigned*)(smoothed + K);         // K
    float* embed_sum = (float*)(cnp + K);                 // K*D
    unsigned short* eh = (unsigned short*)(embed_sum + (size_t)K * D);  // K*D f16

    hipMemsetAsync(counts_i, 0, (K + 4) * sizeof(int), stream);
    hipMemsetAsync(embed_sum, 0, (size_t)K * D * sizeof(float), stream);
    hipMemsetAsync(rkey, 0, (size_t)N_ROWS * sizeof(unsigned long long), stream);

    convert_e<<<(K * D / 8) / 256, 256, 0, stream>>>(embed, eh);
    cnorm_kernel<<<(K + 255) / 256, 256, 0, stream>>>(embed, cnorm, cnp);
    mfma_dist<<<N_ROWS / MROWS, 256, 0, stream>>>(x, eh, cnp, out_idx, idx_i32,
                                                  flag_cnt, flag_list);
    rescore_part<<<dim3(128, RSLICE), 256, 0, stream>>>(x, embed, cnorm, flag_cnt,
                                                        flag_list, rkey);
    rescore_final<<<64, 256, 0, stream>>>(flag_cnt, flag_list, rkey, out_idx, idx_i32);
    hist_kernel<<<64, 256, 0, stream>>>(idx_i32, counts_i);
    scan_cluster_kernel<<<1, 1024, 0, stream>>>(counts_i, cluster_size, offsets, cursor,
                                                out_ncs, smoothed);
    scatter_kernel<<<N_ROWS / 256, 256, 0, stream>>>(idx_i32, cursor, rowlist, codelist);
    segsum_flat<<<N_ROWS / CHUNK, 128, 0, stream>>>(x, rowlist, codelist, embed_sum);
    embed_update_kernel<<<(K * D / 4) / 256, 256, 0, stream>>>(embed_avg, embed_sum, smoothed,
                                                               out_nea, out_ne);
    gather_kernel<<<(N_ROWS * 32) / 256, 256, 0, stream>>>(embed, idx_i32, out_quant);
}

// Round 6
// 291.921 us; speedup vs baseline: 1.2375x; 1.2375x over previous
//
#include <hip/hip_runtime.h>
#include <cstdint>
#include <cstddef>

#define DECAYF 0.99f
#define OMDF   0.01f
#define EPSF   1e-5f
#define MARGIN 0.075f  // fp16 score-error bound

constexpr int N_ROWS = 64 * 2048;   // 131072
constexpr int D      = 128;
constexpr int K      = 1024;
constexpr int RSLICE = 8;           // code slices in rescore (128 codes each)
constexpr int CHUNK  = 64;          // rowlist rows per segsum block
constexpr int MROWS  = 256;         // rows per mfma_dist block

#define GLOBAL_AS __attribute__((address_space(1)))
#define LDS_AS    __attribute__((address_space(3)))

typedef _Float16 f16x8 __attribute__((ext_vector_type(8)));  // 8 f16 = 4 VGPRs
typedef __attribute__((ext_vector_type(4))) float f32x4;

union U8 { f16x8 v; uint4 u; };

__device__ __forceinline__ unsigned short f2h(float f) {
    union { _Float16 h; unsigned short u; } cv;
    cv.h = (_Float16)f;   // RNE
    return cv.u;
}

// ---------------------------------------------------------------------------
// Convert embed fp32 -> fp16 with 2x baked in (exact scale): eh = f16(2*e)
// ---------------------------------------------------------------------------
__global__ __launch_bounds__(256) void convert_e(const float* __restrict__ e,
                                                 unsigned short* __restrict__ eh) {
    int i = blockIdx.x * 256 + threadIdx.x;          // K*D/8 threads
    const float4* e4 = (const float4*)e;
    float4 a = e4[2 * i], b = e4[2 * i + 1];
    uint4 o;
    o.x = (unsigned)f2h(2.f * a.x) | ((unsigned)f2h(2.f * a.y) << 16);
    o.y = (unsigned)f2h(2.f * a.z) | ((unsigned)f2h(2.f * a.w) << 16);
    o.z = (unsigned)f2h(2.f * b.x) | ((unsigned)f2h(2.f * b.y) << 16);
    o.w = (unsigned)f2h(2.f * b.z) | ((unsigned)f2h(2.f * b.w) << 16);
    ((uint4*)eh)[i] = o;
}

// ---------------------------------------------------------------------------
// cnorm[k] = ||embed[k]||^2 (fp32), plus packed f16 hi/lo split of -cnorm
// for MFMA-folded bias: cnp[k] = lo16(-cn_hi) | (lo16(-cn_lo) << 16)
// ---------------------------------------------------------------------------
__global__ __launch_bounds__(256) void cnorm_kernel(const float* __restrict__ embed,
                                                    float* __restrict__ cnorm,
                                                    unsigned* __restrict__ cnp) {
    int k = blockIdx.x * 256 + threadIdx.x;
    if (k >= K) return;
    const float4* e4 = (const float4*)(embed + (size_t)k * D);
    float a0 = 0.f, a1 = 0.f, a2 = 0.f, a3 = 0.f;
#pragma unroll
    for (int i = 0; i < D / 4; ++i) {
        float4 v = e4[i];
        a0 += v.x * v.x; a1 += v.y * v.y; a2 += v.z * v.z; a3 += v.w * v.w;
    }
    float cn = (a0 + a1) + (a2 + a3);
    cnorm[k] = cn;
    unsigned short h = f2h(-cn);
    union { unsigned short u; _Float16 hf; } cvh; cvh.u = h;
    float hr = (float)cvh.hf;
    unsigned short l = f2h(-cn - hr);
    cnp[k] = (unsigned)h | ((unsigned)l << 16);
}

// ---------------------------------------------------------------------------
// MFMA distance (fp16) + approx argmax with best/best2 margin flagging.
//  - 256 rows/block, 4 waves; B staged in LDS via global_load_lds (dbuf,
//    64 codes = 16 KB per buffer) -> one eh stream per BLOCK, not per wave
//  - XOR block-swizzle (b ^= row&7 on 16B blocks) applied on the GLOBAL
//    source address (global_load_lds writes linearly, m104/m173) and on the
//    ds_read side -> 2-way bank aliasing (free)
//  - staging buffers alias the merge arrays (used only after the K loop)
//    -> 52 KB LDS/block -> 3 blocks/CU
//  - -||e||^2 folded into MFMA via hi/lo f16 bias row
// ---------------------------------------------------------------------------
__global__ __launch_bounds__(256) void mfma_dist(const float* __restrict__ x,
                                                 const unsigned short* __restrict__ eh,
                                                 const unsigned* __restrict__ cnp,
                                                 float* __restrict__ out_idx,
                                                 int* __restrict__ idx_i32,
                                                 int* __restrict__ flag_cnt,
                                                 int* __restrict__ flag_list) {
    __shared__ __align__(16) float smem[MROWS * 17 * 3];   // 52224 B
    // aliases: staging (2 x 16 KB) lives at the front, used only during K loop
    unsigned short* bstage = (unsigned short*)smem;
    float* sb1 = smem;
    float* sb2 = smem + MROWS * 17;
    float* sid = smem + MROWS * 17 * 2;

    const int tid = threadIdx.x;
    const int wave = tid >> 6;
    const int lane = tid & 63;
    const int l15 = lane & 15;
    const int quad = lane >> 4;
    const int rowbase = blockIdx.x * MROWS + wave * 64;

    // preload A-frags: 4 sets x 4 d-chunks, convert fp32->fp16 inline
    f16x8 a[4][4];
    {
        const float4* x4 = (const float4*)x;
#pragma unroll
        for (int s = 0; s < 4; ++s) {
            int row = rowbase + s * 16 + l15;
#pragma unroll
            for (int c = 0; c < 4; ++c) {
                size_t b4 = ((size_t)row * D + c * 32 + quad * 8) >> 2;
                float4 p = x4[b4], q = x4[b4 + 1];
                f16x8 f;
                f[0] = (_Float16)p.x; f[1] = (_Float16)p.y;
                f[2] = (_Float16)p.z; f[3] = (_Float16)p.w;
                f[4] = (_Float16)q.x; f[5] = (_Float16)q.y;
                f[6] = (_Float16)q.z; f[7] = (_Float16)q.w;
                a[s][c] = f;
            }
        }
    }

    // constant A-frag for the bias row: k-slots 0,1 = 1.0 (quad 0 lanes only)
    U8 acn;
    acn.u.x = (quad == 0) ? 0x3C003C00u : 0u;
    acn.u.y = 0u; acn.u.z = 0u; acn.u.w = 0u;

    float b1[4][4], b2[4][4], idf[4][4];
#pragma unroll
    for (int s = 0; s < 4; ++s)
#pragma unroll
        for (int r = 0; r < 4; ++r) { b1[s][r] = -3.4e38f; b2[s][r] = -3.4e38f; idf[s][r] = 0.f; }

    // stage 64 codes (16 KB) into buffer `buf`; cp = 64-code group index.
    // LDS dest is linear (wave-uniform base, HW adds lane*16); the global
    // source pre-applies the block swizzle gblk = bslot ^ (row&7).
    auto stage = [&](int buf, int cp) {
#pragma unroll
        for (int j = 0; j < 4; ++j) {
            int sec = wave * 4 + j;                  // 0..15, 1 KB sectors
            int row = sec * 4 + (lane >> 4);         // 0..63 (code within group)
            int gblk = (lane & 15) ^ (row & 7);
            const char* g = (const char*)eh + (size_t)cp * 16384 + row * 256 + gblk * 16;
            char* l = (char*)bstage + buf * 16384 + sec * 1024;
            __builtin_amdgcn_global_load_lds((const GLOBAL_AS void*)g,
                                             (LDS_AS void*)l, 16, 0, 0);
        }
    };

    // read B fragment for chunk k (16 codes) of buffer `buf` from LDS
    auto load_b = [&](f16x8* dst, unsigned& cnw, int buf, int k, int cb) {
        const unsigned short* bb = bstage + buf * 8192 + k * 2048 + l15 * 128;
#pragma unroll
        for (int c = 0; c < 4; ++c) {
            int blk = (c * 4 + quad) ^ (l15 & 7);
            dst[c] = *(const f16x8*)(bb + blk * 8);
        }
        cnw = cnp[cb + l15];
    };

    auto compute = [&](const f16x8* bfr, unsigned cnw, float colf) {
        U8 bcn;
        bcn.u.x = (quad == 0) ? cnw : 0u;
        bcn.u.y = 0u; bcn.u.z = 0u; bcn.u.w = 0u;
        f32x4 zero = {0.f, 0.f, 0.f, 0.f};
        f32x4 cnacc = __builtin_amdgcn_mfma_f32_16x16x32_f16(acn.v, bcn.v, zero, 0, 0, 0);
#pragma unroll
        for (int s = 0; s < 4; ++s) {
            f32x4 acc = cnacc;
#pragma unroll
            for (int c = 0; c < 4; ++c)
                acc = __builtin_amdgcn_mfma_f32_16x16x32_f16(a[s][c], bfr[c], acc, 0, 0, 0);
#pragma unroll
            for (int r = 0; r < 4; ++r) {
                float sc = acc[r];               // = 2*x.e - ||e||^2 directly
                float old = b1[s][r];
                b1[s][r] = fmaxf(old, sc);
                b2[s][r] = fmaxf(fminf(sc, old), b2[s][r]);
                idf[s][r] = (sc > old) ? colf : idf[s][r];
            }
        }
    };

    constexpr int ITERS = K / 64;   // 16
    stage(0, 0);
    __syncthreads();                // drains vmcnt(0) before barrier

    for (int cp = 0; cp < ITERS; ++cp) {
        if (cp + 1 < ITERS) stage((cp + 1) & 1, cp + 1);
        const int buf = cp & 1;
        const int base = cp * 64;
        f16x8 bf0[4], bf1[4];
        unsigned cw0, cw1;
        load_b(bf0, cw0, buf, 0, base);
        load_b(bf1, cw1, buf, 1, base + 16);
        compute(bf0, cw0, (float)(base + l15));
        compute(bf1, cw1, (float)(base + 16 + l15));
        load_b(bf0, cw0, buf, 2, base + 32);
        load_b(bf1, cw1, buf, 3, base + 48);
        compute(bf0, cw0, (float)(base + 32 + l15));
        compute(bf1, cw1, (float)(base + 48 + l15));
        __syncthreads();            // next-buffer staging landed; this buffer free
    }

    // K loop done; final barrier above separates staging reads from merge
    // writes (the arrays alias). dump per-lane candidates: row lr has 16
    // candidates (one per l15)
#pragma unroll
    for (int s = 0; s < 4; ++s)
#pragma unroll
        for (int r = 0; r < 4; ++r) {
            int lr = wave * 64 + s * 16 + quad * 4 + r;
            sb1[lr * 17 + l15] = b1[s][r];
            sb2[lr * 17 + l15] = b2[s][r];
            sid[lr * 17 + l15] = idf[s][r];
        }
    __syncthreads();

    // one thread per row: merge 16 (b1,b2,idx) candidates
    {
        float bs = sb1[tid * 17], ss = sb2[tid * 17], bi = sid[tid * 17];
#pragma unroll
        for (int j = 1; j < 16; ++j) {
            float v = sb1[tid * 17 + j];
            float w = sb2[tid * 17 + j];
            float id = sid[tid * 17 + j];
            if (v > bs) { ss = fmaxf(bs, w); bi = id; bs = v; }
            else {
                ss = fmaxf(ss, v);
                if (v == bs && id < bi) bi = id;
            }
        }
        int grow = blockIdx.x * MROWS + tid;
        out_idx[grow] = bi;
        idx_i32[grow] = (int)bi;
        if (bs - ss < MARGIN) {
            int p = atomicAdd(flag_cnt, 1);
            flag_list[p] = grow;
        }
    }
}

// ---------------------------------------------------------------------------
// Exact fp32 rescore of flagged rows, CODE-SLICED across blocks.
// grid = (chunks grid-stride, RSLICE). Each block: 128 rows x 128 codes.
// Partial per-row argmax merged via packed u64 atomicMax:
//   key = orderable(score) << 32 | (0xFFFF - idx)   (max score, min idx on tie)
// ---------------------------------------------------------------------------
__global__ __launch_bounds__(256, 1) void rescore_part(const float* __restrict__ x,
                                                       const float* __restrict__ embed,
                                                       const float* __restrict__ cnorm,
                                                       const int* __restrict__ flag_cnt,
                                                       const int* __restrict__ flag_list,
                                                       unsigned long long* __restrict__ rkey) {
    __shared__ float xs[128][132];
    __shared__ float es[128][132];

    const int tid = threadIdx.x;
    const int tx = tid & 15;
    const int ty = tid >> 4;
    const int sl = blockIdx.y;                 // code slice: [sl*128, sl*128+128)
    const int cnt = *flag_cnt;
    const int nch = (cnt + 127) >> 7;

    for (int ch = blockIdx.x; ch < nch; ch += gridDim.x) {
        __syncthreads();
        // stage 128 flagged x rows
        {
            const float4* x4 = (const float4*)x;
#pragma unroll
            for (int it = 0; it < 16; ++it) {
                int idx = it * 256 + tid;
                int slot = idx >> 5, c4 = idx & 31;
                int fi = ch * 128 + slot;
                int grow = flag_list[fi < cnt ? fi : cnt - 1];
                float4 v = x4[(size_t)grow * 32 + c4];
                *(float4*)&xs[slot][c4 * 4] = v;
            }
        }
        // stage this slice's 128 embed rows
        {
            const float4* e4 = (const float4*)embed;
            const size_t base4 = (size_t)sl * 128 * 32;
#pragma unroll
            for (int it = 0; it < 16; ++it) {
                int idx = it * 256 + tid;
                int row = idx >> 5, c4 = idx & 31;
                float4 v = e4[base4 + idx];
                *(float4*)&es[row][c4 * 4] = v;
            }
        }
        float cn[8];
#pragma unroll
        for (int c = 0; c < 8; ++c) cn[c] = cnorm[sl * 128 + tx + 16 * c];
        __syncthreads();

        float acc[8][8];
#pragma unroll
        for (int r = 0; r < 8; ++r)
#pragma unroll
            for (int c = 0; c < 8; ++c) acc[r][c] = 0.f;

#pragma unroll 2
        for (int d4 = 0; d4 < 32; ++d4) {
            float4 av[8], bv[8];
#pragma unroll
            for (int r = 0; r < 8; ++r) av[r] = *(const float4*)&xs[ty + 16 * r][4 * d4];
#pragma unroll
            for (int c = 0; c < 8; ++c) bv[c] = *(const float4*)&es[tx + 16 * c][4 * d4];
#pragma unroll
            for (int r = 0; r < 8; ++r)
#pragma unroll
                for (int c = 0; c < 8; ++c) {
                    acc[r][c] = fmaf(av[r].x, bv[c].x, acc[r][c]);
                    acc[r][c] = fmaf(av[r].y, bv[c].y, acc[r][c]);
                    acc[r][c] = fmaf(av[r].z, bv[c].z, acc[r][c]);
                    acc[r][c] = fmaf(av[r].w, bv[c].w, acc[r][c]);
                }
        }

        float best[8];
        int bidx[8];
#pragma unroll
        for (int r = 0; r < 8; ++r) { best[r] = -3.4e38f; bidx[r] = 0; }
#pragma unroll
        for (int r = 0; r < 8; ++r)
#pragma unroll
            for (int c = 0; c < 8; ++c) {
                float s = 2.0f * acc[r][c] - cn[c];
                // codes ascend with c, so strict > keeps the lowest tied index
                if (s > best[r]) { best[r] = s; bidx[r] = sl * 128 + tx + 16 * c; }
            }

        __syncthreads();
        float* sbest = &es[0][0];
        int*   sidx  = (int*)&xs[0][0];
#pragma unroll
        for (int r = 0; r < 8; ++r) {
            int row = ty + 16 * r;
            sbest[row * 16 + tx] = best[r];
            sidx[row * 16 + tx] = bidx[r];
        }
        __syncthreads();
        if (tid < 128) {
            float bs = sbest[tid * 16];
            int bi = sidx[tid * 16];
#pragma unroll
            for (int j = 1; j < 16; ++j) {
                float s = sbest[tid * 16 + j];
                int id = sidx[tid * 16 + j];
                if (s > bs || (s == bs && id < bi)) { bs = s; bi = id; }
            }
            int fi = ch * 128 + tid;
            if (fi < cnt) {
                unsigned ub = __float_as_uint(bs);
                ub = (ub & 0x80000000u) ? ~ub : (ub | 0x80000000u);
                unsigned long long key =
                    ((unsigned long long)ub << 32) | (unsigned)(0xFFFFu - bi);
                atomicMax(&rkey[fi], key);
            }
        }
    }
}

__global__ __launch_bounds__(256) void rescore_final(const int* __restrict__ flag_cnt,
                                                     const int* __restrict__ flag_list,
                                                     const unsigned long long* __restrict__ rkey,
                                                     float* __restrict__ out_idx,
                                                     int* __restrict__ idx_i32) {
    const int cnt = *flag_cnt;
    for (int i = blockIdx.x * 256 + threadIdx.x; i < cnt; i += gridDim.x * 256) {
        unsigned long long key = rkey[i];
        int bi = 0xFFFF - (int)(key & 0xFFFFFFFFull);
        int grow = flag_list[i];
        out_idx[grow] = (float)bi;
        idx_i32[grow] = bi;
    }
}

// ---------------------------------------------------------------------------
// Histogram of final indices (LDS-privatized)
// ---------------------------------------------------------------------------
__global__ __launch_bounds__(256) void hist_kernel(const int* __restrict__ idx_i32,
                                                   int* __restrict__ counts_i) {
    __shared__ int h[K];
    for (int i = threadIdx.x; i < K; i += 256) h[i] = 0;
    __syncthreads();
    for (int row = blockIdx.x * 256 + threadIdx.x; row < N_ROWS; row += gridDim.x * 256)
        atomicAdd(&h[idx_i32[row]], 1);
    __syncthreads();
    for (int i = threadIdx.x; i < K; i += 256)
        if (h[i]) atomicAdd(&counts_i[i], h[i]);
}

// ---------------------------------------------------------------------------
// scan counts -> offsets/cursor; ncs, total, smoothed (1 block, 1024 thr)
// ---------------------------------------------------------------------------
__global__ __launch_bounds__(1024) void scan_cluster_kernel(const int* __restrict__ counts_i,
                                                            const float* __restrict__ cluster_size,
                                                            int* __restrict__ offsets,
                                                            int* __restrict__ cursor,
                                                            float* __restrict__ out_ncs,
                                                            float* __restrict__ smoothed) {
    __shared__ int s[1024];
    __shared__ float red[16];
    __shared__ float total_s;
    int k = threadIdx.x;
    int c = counts_i[k];
    s[k] = c;
    __syncthreads();
    for (int off = 1; off < 1024; off <<= 1) {
        int v = (k >= off) ? s[k - off] : 0;
        __syncthreads();
        s[k] += v;
        __syncthreads();
    }
    int offx = s[k] - c;   // exclusive
    offsets[k] = offx;
    cursor[k] = offx;

    float ncs = cluster_size[k] * DECAYF + OMDF * (float)c;
    out_ncs[k] = ncs;

    float v = ncs;
#pragma unroll
    for (int off = 32; off >= 1; off >>= 1) v += __shfl_down(v, off, 64);
    if ((k & 63) == 0) red[k >> 6] = v;
    __syncthreads();
    if (k < 16) {
        float t = red[k];
#pragma unroll
        for (int off = 8; off >= 1; off >>= 1) t += __shfl_down(t, off, 16);
        if (k == 0) total_s = t;
    }
    __syncthreads();
    float total = total_s;
    smoothed[k] = (ncs + EPSF) / (total + (float)K * EPSF) * total;
}

// ---------------------------------------------------------------------------
// scatter row ids (and their code) into per-code segments
// ---------------------------------------------------------------------------
__global__ __launch_bounds__(256) void scatter_kernel(const int* __restrict__ idx_i32,
                                                      int* __restrict__ cursor,
                                                      int* __restrict__ rowlist,
                                                      int* __restrict__ codelist) {
    int row = blockIdx.x * 256 + threadIdx.x;
    int code = idx_i32[row];
    int pos = atomicAdd(&cursor[code], 1);
    rowlist[pos] = row;
    codelist[pos] = code;
}

// ---------------------------------------------------------------------------
// Flat segmented gather-sum: each block owns exactly CHUNK consecutive
// rowlist entries (perfect balance). Register run-accumulation; atomic
// flush only at run boundaries.
// ---------------------------------------------------------------------------
__global__ __launch_bounds__(128) void segsum_flat(const float* __restrict__ x,
                                                   const int* __restrict__ rowlist,
                                                   const int* __restrict__ codelist,
                                                   float* __restrict__ embed_sum) {
    const int d = threadIdx.x;
    const int lo = blockIdx.x * CHUNK;

    float acc = 0.f;
    int cur = codelist[lo];
    for (int i = lo; i < lo + CHUNK; i += 8) {
        int r[8], c[8];
        float v[8];
#pragma unroll
        for (int j = 0; j < 8; ++j) {
            r[j] = rowlist[i + j];
            c[j] = codelist[i + j];
        }
#pragma unroll
        for (int j = 0; j < 8; ++j) v[j] = x[(size_t)r[j] * D + d];
#pragma unroll
        for (int j = 0; j < 8; ++j) {
            if (c[j] != cur) {
                atomicAdd(&embed_sum[(size_t)cur * D + d], acc);
                acc = 0.f;
                cur = c[j];
            }
            acc += v[j];
        }
    }
    atomicAdd(&embed_sum[(size_t)cur * D + d], acc);
}

// ---------------------------------------------------------------------------
// new_embed_avg / new_embed
// ---------------------------------------------------------------------------
__global__ __launch_bounds__(256) void embed_update_kernel(const float* __restrict__ embed_avg,
                                                           const float* __restrict__ embed_sum,
                                                           const float* __restrict__ smoothed,
                                                           float* __restrict__ out_nea,
                                                           float* __restrict__ out_ne) {
    int t = blockIdx.x * 256 + threadIdx.x;
    float4 ea = ((const float4*)embed_avg)[t];
    float4 es = ((const float4*)embed_sum)[t];
    float sm = smoothed[t >> 5];
    float4 nea;
    nea.x = ea.x * DECAYF + OMDF * es.x;
    nea.y = ea.y * DECAYF + OMDF * es.y;
    nea.z = ea.z * DECAYF + OMDF * es.z;
    nea.w = ea.w * DECAYF + OMDF * es.w;
    ((float4*)out_nea)[t] = nea;
    float4 ne;
    ne.x = nea.x / sm; ne.y = nea.y / sm; ne.z = nea.z / sm; ne.w = nea.w / sm;
    ((float4*)out_ne)[t] = ne;
}

// ---------------------------------------------------------------------------
// quantized[row] = embed[idx[row]]  (runs last: overwrites rkey/codelist scratch)
// ---------------------------------------------------------------------------
__global__ __launch_bounds__(256) void gather_kernel(const float* __restrict__ embed,
                                                     const int* __restrict__ idx_i32,
                                                     float* __restrict__ quant) {
    int t = blockIdx.x * 256 + threadIdx.x;
    int row = t >> 5;
    int j = t & 31;
    int k = idx_i32[row];
    ((float4*)quant)[(size_t)row * 32 + j] = ((const float4*)embed)[(size_t)k * 32 + j];
}

// ---------------------------------------------------------------------------
extern "C" void kernel_launch(void* const* d_in, const int* in_sizes, int n_in,
                              void* d_out, int out_size, void* d_ws, size_t ws_size,
                              hipStream_t stream) {
    const float* x            = (const float*)d_in[0];
    const float* embed        = (const float*)d_in[1];
    const float* embed_avg    = (const float*)d_in[2];
    const float* cluster_size = (const float*)d_in[3];

    float* out       = (float*)d_out;
    float* out_quant = out;
    float* out_idx   = out_quant + (size_t)N_ROWS * D;
    float* out_ne    = out_idx + N_ROWS;
    float* out_ncs   = out_ne + (size_t)K * D;
    float* out_nea   = out_ncs + K;

    // scratch in the quantized output region (overwritten by gather_kernel last):
    //   rkey: u64 argmax keys for flagged rows (1 MB)
    //   codelist: per-rowlist-slot code ids (0.5 MB)
    unsigned long long* rkey = (unsigned long long*)out_quant;
    int* codelist = (int*)(rkey + N_ROWS);

    // workspace (~2.4 MB)
    int*   counts_i  = (int*)d_ws;                        // K
    int*   flag_cnt  = counts_i + K;                      // 1 (+3 pad)
    int*   idx_i32   = counts_i + K + 4;                  // N
    int*   flag_list = idx_i32 + N_ROWS;                  // N
    int*   offsets   = flag_list + N_ROWS;                // K
    int*   cursor    = offsets + K;                       // K
    int*   rowlist   = cursor + K;                        // N
    float* cnorm     = (float*)(rowlist + N_ROWS);        // K
    float* smoothed  = cnorm + K;                         // K
    unsigned* cnp    = (unsigned*)(smoothed + K);         // K
    float* embed_sum = (float*)(cnp + K);                 // K*D
    unsigned short* eh = (unsigned short*)(embed_sum + (size_t)K * D);  // K*D f16

    hipMemsetAsync(counts_i, 0, (K + 4) * sizeof(int), stream);
    hipMemsetAsync(embed_sum, 0, (size_t)K * D * sizeof(float), stream);
    hipMemsetAsync(rkey, 0, (size_t)N_ROWS * sizeof(unsigned long long), stream);

    convert_e<<<(K * D / 8) / 256, 256, 0, stream>>>(embed, eh);
    cnorm_kernel<<<(K + 255) / 256, 256, 0, stream>>>(embed, cnorm, cnp);
    mfma_dist<<<N_ROWS / MROWS, 256, 0, stream>>>(x, eh, cnp, out_idx, idx_i32,
                                                  flag_cnt, flag_list);
    rescore_part<<<dim3(128, RSLICE), 256, 0, stream>>>(x, embed, cnorm, flag_cnt,
                                                        flag_list, rkey);
    rescore_final<<<64, 256, 0, stream>>>(flag_cnt, flag_list, rkey, out_idx, idx_i32);
    hist_kernel<<<64, 256, 0, stream>>>(idx_i32, counts_i);
    scan_cluster_kernel<<<1, 1024, 0, stream>>>(counts_i, cluster_size, offsets, cursor,
                                                out_ncs, smoothed);
    scatter_kernel<<<N_ROWS / 256, 256, 0, stream>>>(idx_i32, cursor, rowlist, codelist);
    segsum_flat<<<N_ROWS / CHUNK, 128, 0, stream>>>(x, rowlist, codelist, embed_sum);
    embed_update_kernel<<<(K * D / 4) / 256, 256, 0, stream>>>(embed_avg, embed_sum, smoothed,
                                                               out_nea, out_ne);
    gather_kernel<<<(N_ROWS * 32) / 256, 256, 0, stream>>>(embed, idx_i32, out_quant);
}